// Round 12
// baseline (111.624 us; speedup 1.0000x reference)
//
#include <hip/hip_runtime.h>
#include <hip/hip_bf16.h>
#include <stdint.h>

// Problem constants: B=2, L=2048, E=1024, H=16, HD=64, G=4.
#define L_SEQ 2048
#define MTOT  4096   // B*L
#define EDIM  1024

typedef __attribute__((ext_vector_type(8))) short bf16x8;    // 8 bf16 (4 VGPRs)
typedef __attribute__((ext_vector_type(4))) float f32x4;
typedef __attribute__((ext_vector_type(16))) float f32x16;   // 32x32 MFMA acc
typedef __attribute__((ext_vector_type(4))) float float4v;
typedef __attribute__((ext_vector_type(4))) unsigned short us4;

__device__ __forceinline__ unsigned short f2b(float f) {
    union { float f; unsigned u; } v; v.f = f;
    return (unsigned short)((v.u + 0x7FFFu + ((v.u >> 16) & 1u)) >> 16);  // RNE
}
__device__ __forceinline__ float b2f(unsigned short h) {
    union { unsigned u; float f; } v; v.u = ((unsigned)h) << 16;
    return v.f;
}
__device__ __forceinline__ unsigned cvtpk(float lo, float hi) {   // RNE pack
    unsigned r;
    asm("v_cvt_pk_bf16_f32 %0, %1, %2" : "=v"(r) : "v"(lo), "v"(hi));
    return r;
}

// ---------------------------------------------------------------------------
// wprep: convert W1 (stitched [Wv rows 0..255 ; Wq rows 256..1023]) and Wo
//        to bf16. Blocks >= 2048 compute the composed FIR taps.  (R7-verified)
// ---------------------------------------------------------------------------
__global__ __launch_bounds__(256) void wprep_kernel(
    const float* __restrict__ Wq, const float* __restrict__ Wv,
    const float* __restrict__ Wo,
    unsigned short* __restrict__ W1b, unsigned short* __restrict__ Wob,
    const float* __restrict__ q3w, const float* __restrict__ q3b,
    const float* __restrict__ v3w, const float* __restrict__ v3b,
    const float* __restrict__ q5w, const float* __restrict__ q5b,
    const float* __restrict__ v5w, const float* __restrict__ v5b,
    const float* __restrict__ q7w, const float* __restrict__ q7b,
    const float* __restrict__ v7w, const float* __restrict__ v7b,
    float* __restrict__ H, float* __restrict__ Beff, float* __restrict__ Corr)
{
    if (blockIdx.x >= 2048) {
        // taps: dwconv taps h[i]=w[k-1-i]; chain h = hq (*) hv (len 2k-1<=13),
        // beff = vb + qb*sum(vw); boundary (l<k-1): intermediate zero-pad
        // drops qb for taps i>l -> Corr[l][ch] = qb*sum_{i=l+1..} hv[i].
        int ch = (blockIdx.x - 2048) * 256 + threadIdx.x;   // [0,768)
        int g = ch >> 8, d = ch & 63, k = 3 + 2 * g;
        const float* qw = (g == 0) ? q3w : (g == 1) ? q5w : q7w;
        const float* qb = (g == 0) ? q3b : (g == 1) ? q5b : q7b;
        const float* vw = (g == 0) ? v3w : (g == 1) ? v5w : v7w;
        const float* vb = (g == 0) ? v3b : (g == 1) ? v5b : v7b;

        float hq[7], hv[7];
        for (int i = 0; i < 7; ++i) { hq[i] = 0.f; hv[i] = 0.f; }
        for (int i = 0; i < k; ++i) {
            hq[i] = qw[d * k + (k - 1 - i)];
            hv[i] = vw[d * k + (k - 1 - i)];
        }
        float h[13];
        for (int i = 0; i < 13; ++i) h[i] = 0.f;
        for (int a = 0; a < 7; ++a)
            for (int b = 0; b < 7; ++b)
                h[a + b] += hq[a] * hv[b];
        for (int i = 0; i < 13; ++i) H[i * 768 + ch] = h[i];

        float sv = 0.f;
        for (int j = 0; j < k; ++j) sv += vw[d * k + j];
        Beff[ch] = qb[d] * sv + vb[d];

        for (int l = 0; l < 6; ++l) {
            float s2 = 0.f;
            for (int i = l + 1; i < 7; ++i) s2 += hv[i];
            Corr[l * 768 + ch] = qb[d] * s2;
        }
        return;
    }
    const int WQ = (EDIM * EDIM) / 4;   // 262,144 quads per matrix
    int i = blockIdx.x * 256 + threadIdx.x;
    const float* src;
    unsigned short* dst;
    int j;
    if (i < WQ) {
        j = i * 4;
        int row = j >> 10;                 // /1024
        src = (row < 256) ? Wv : Wq;       // stitched W1
        dst = W1b;
    } else {
        j = (i - WQ) * 4; src = Wo; dst = Wob;
    }
    float4v v = *(const float4v*)(src + j);
    us4 o;
    o[0] = f2b(v[0]); o[1] = f2b(v[1]); o[2] = f2b(v[2]); o[3] = f2b(v[3]);
    *(us4*)(dst + j) = o;
}

// ---------------------------------------------------------------------------
// GEMM, zero-LDS / zero-barrier: C[4096,1024] = A * BT^T.
//   R11 counters: MfmaUtil 6.4%, VALU 7.5%, HBM 5.7% -> ~90% stall from the
//   monolithic-staging barrier+vmcnt chain (null across R3-R11 variants).
//   Here each wave computes a 64x64 tile reading MFMA fragments DIRECTLY
//   from global (L2-resident operands: W 2MB, x 16MB, T/V 8MB). No s_barrier,
//   no LDS, no bank conflicts; compiler tracks per-register vmcnt and
//   unroll-4 software-pipelines ~4 K-steps of loads ahead of their MFMAs.
//   Block = 256 thr = 4 waves (2x2 of 64x64 -> 128x128 block tile);
//   grid (8,32) = 256 blocks, XCD-remapped. Per K=16 step per wave:
//   2 A-frag loads + 2 B-frag loads + 4 mfma_32x32x16 (frag map verified
//   m74/m101 + R10: A/B row=lane&31, K-half=lane>>5; C/D col=lane&31,
//   row=(reg&3)+8*(reg>>2)+4*(lane>>5)).
//   TA=1: A raw fp32 (x), 32B/lane, packed via v_cvt_pk_bf16_f32.
//   TA=0: A bf16; K-loop split at 256 (cols<256 from Ab0=T, else Ab1=V).
// OUT_MODE 0: bf16 store. OUT_MODE 1: f32 store + bias[col].
// ---------------------------------------------------------------------------
template <int TA, int OUT_MODE>
__global__ __launch_bounds__(256) void gemm_nl(
    const float* __restrict__ Af,
    const unsigned short* __restrict__ Ab0, const unsigned short* __restrict__ Ab1,
    const unsigned short* __restrict__ BT,
    unsigned short* __restrict__ Cb, float* __restrict__ Cf,
    const float* __restrict__ bias)
{
    // XCD-aware remap (256 blocks, %8==0 -> bijective chunked).
    int orig = blockIdx.y * 8 + blockIdx.x;
    int wg   = (orig & 7) * 32 + (orig >> 3);
    const int m0 = (wg >> 3) * 128, n0 = (wg & 7) * 128;

    const int tid  = threadIdx.x;
    const int wid  = tid >> 6;
    const int lane = tid & 63;
    const int wr   = wid >> 1, wc = wid & 1;      // 2x2 waves, 64x64 tiles
    const int l31  = lane & 31, hi = lane >> 5;

    f32x16 acc[2][2] = {};

    const unsigned short* Bp0 = BT + (size_t)(n0 + wc * 64 + l31) * EDIM + hi * 8;
    const unsigned short* Bp1 = Bp0 + (size_t)32 * EDIM;

#define MFMA4(A0, A1, B0, B1)                                                   \
    acc[0][0] = __builtin_amdgcn_mfma_f32_32x32x16_bf16(A0, B0, acc[0][0], 0, 0, 0); \
    acc[0][1] = __builtin_amdgcn_mfma_f32_32x32x16_bf16(A0, B1, acc[0][1], 0, 0, 0); \
    acc[1][0] = __builtin_amdgcn_mfma_f32_32x32x16_bf16(A1, B0, acc[1][0], 0, 0, 0); \
    acc[1][1] = __builtin_amdgcn_mfma_f32_32x32x16_bf16(A1, B1, acc[1][1], 0, 0, 0)

    if (TA) {
        const float* Ap0 = Af + (size_t)(m0 + wr * 64 + l31) * EDIM + hi * 8;
        const float* Ap1 = Ap0 + (size_t)32 * EDIM;
#pragma unroll 4
        for (int k0 = 0; k0 < EDIM; k0 += 16) {
            f32x4 al0 = *(const f32x4*)(Ap0 + k0);
            f32x4 ah0 = *(const f32x4*)(Ap0 + k0 + 4);
            f32x4 al1 = *(const f32x4*)(Ap1 + k0);
            f32x4 ah1 = *(const f32x4*)(Ap1 + k0 + 4);
            bf16x8 b0 = *(const bf16x8*)(Bp0 + k0);
            bf16x8 b1 = *(const bf16x8*)(Bp1 + k0);
            union { unsigned u[4]; bf16x8 v; } a0, a1;
            a0.u[0] = cvtpk(al0[0], al0[1]); a0.u[1] = cvtpk(al0[2], al0[3]);
            a0.u[2] = cvtpk(ah0[0], ah0[1]); a0.u[3] = cvtpk(ah0[2], ah0[3]);
            a1.u[0] = cvtpk(al1[0], al1[1]); a1.u[1] = cvtpk(al1[2], al1[3]);
            a1.u[2] = cvtpk(ah1[0], ah1[1]); a1.u[3] = cvtpk(ah1[2], ah1[3]);
            MFMA4(a0.v, a1.v, b0, b1);
        }
    } else {
        const size_t aoff = (size_t)(m0 + wr * 64 + l31) * EDIM + hi * 8;
        const unsigned short* Ap = Ab0 + aoff;        // K-cols [0,256): T
#pragma unroll 4
        for (int k0 = 0; k0 < 256; k0 += 16) {
            bf16x8 a0 = *(const bf16x8*)(Ap + k0);
            bf16x8 a1 = *(const bf16x8*)(Ap + 32 * EDIM + k0);
            bf16x8 b0 = *(const bf16x8*)(Bp0 + k0);
            bf16x8 b1 = *(const bf16x8*)(Bp1 + k0);
            MFMA4(a0, a1, b0, b1);
        }
        const unsigned short* Aq = Ab1 + aoff;        // K-cols [256,1024): V
#pragma unroll 4
        for (int k0 = 256; k0 < EDIM; k0 += 16) {
            bf16x8 a0 = *(const bf16x8*)(Aq + k0);
            bf16x8 a1 = *(const bf16x8*)(Aq + 32 * EDIM + k0);
            bf16x8 b0 = *(const bf16x8*)(Bp0 + k0);
            bf16x8 b1 = *(const bf16x8*)(Bp1 + k0);
            MFMA4(a0, a1, b0, b1);
        }
    }
#undef MFMA4

    // epilogue: C/D col=lane&31, row=(reg&3)+8*(reg>>2)+4*(lane>>5) [verified]
#pragma unroll
    for (int mi = 0; mi < 2; ++mi) {
#pragma unroll
        for (int ni = 0; ni < 2; ++ni) {
            int col = n0 + wc * 64 + ni * 32 + l31;
            float bv = (OUT_MODE == 1) ? bias[col] : 0.f;
#pragma unroll
            for (int q = 0; q < 4; ++q) {
                int rowb = m0 + wr * 64 + mi * 32 + 8 * q + 4 * hi;
#pragma unroll
                for (int j = 0; j < 4; ++j) {
                    float v = acc[mi][ni][q * 4 + j];
                    if (OUT_MODE == 0) {
                        Cb[(size_t)(rowb + j) * EDIM + col] = f2b(v);
                    } else {
                        Cf[(size_t)(rowb + j) * EDIM + col] = v + bv;
                    }
                }
            }
        }
    }
}

// ---------------------------------------------------------------------------
// conv: causal FIR on cols 256..1023 (v0 cols read from T by gemm2's first
// K-loop). Thread: 4 channels x 2 consecutive positions.  (R7-verified)
// ---------------------------------------------------------------------------
__global__ __launch_bounds__(256) void conv_kernel(
    const unsigned short* __restrict__ T, unsigned short* __restrict__ V,
    const float* __restrict__ H, const float* __restrict__ Beff,
    const float* __restrict__ Corr)
{
    unsigned w  = blockIdx.x * 256 + threadIdx.x;   // 2048 rowpairs x 192 quads
    unsigned rp = w / 192u;
    int c4 = (int)(w - rp * 192u);
    int m  = (int)rp * 2;                           // pair never crosses batch
    int ch = c4 * 4;                                // [0,768)
    int e0 = 256 + ch;
    const unsigned short* tp = T + (size_t)m * EDIM + e0;
    unsigned short*       vp = V + (size_t)m * EDIM + e0;
    int l  = m & (L_SEQ - 1);
    float4v b4 = *(const float4v*)(Beff + ch);
    float4v acc0 = b4, acc1 = b4;

    {
        float4v h = *(const float4v*)(H + ch);      // H[0], row m+1
        us4 t = *(const us4*)(tp + EDIM);
        acc1[0] += h[0] * b2f(t[0]); acc1[1] += h[1] * b2f(t[1]);
        acc1[2] += h[2] * b2f(t[2]); acc1[3] += h[3] * b2f(t[3]);
    }
    int ni = (l < 12) ? l : 12;
    for (int i = 0; i <= ni; ++i) {                 // row m-i, taps h[i]/h[i+1]
        us4 t = *(const us4*)(tp - (size_t)i * EDIM);
        float4v h0 = *(const float4v*)(H + i * 768 + ch);
        acc0[0] += h0[0] * b2f(t[0]); acc0[1] += h0[1] * b2f(t[1]);
        acc0[2] += h0[2] * b2f(t[2]); acc0[3] += h0[3] * b2f(t[3]);
        if (i < 12) {
            float4v h1 = *(const float4v*)(H + (i + 1) * 768 + ch);
            acc1[0] += h1[0] * b2f(t[0]); acc1[1] += h1[1] * b2f(t[1]);
            acc1[2] += h1[2] * b2f(t[2]); acc1[3] += h1[3] * b2f(t[3]);
        }
    }
    if (l < 6) {   // bias boundary correction (intermediate zero-padding)
        float4v c = *(const float4v*)(Corr + l * 768 + ch);
        acc0[0] -= c[0]; acc0[1] -= c[1]; acc0[2] -= c[2]; acc0[3] -= c[3];
    }
    if (l + 1 < 6) {
        float4v c = *(const float4v*)(Corr + (l + 1) * 768 + ch);
        acc1[0] -= c[0]; acc1[1] -= c[1]; acc1[2] -= c[2]; acc1[3] -= c[3];
    }
    us4 o0, o1;
    o0[0] = f2b(acc0[0]); o0[1] = f2b(acc0[1]); o0[2] = f2b(acc0[2]); o0[3] = f2b(acc0[3]);
    o1[0] = f2b(acc1[0]); o1[1] = f2b(acc1[1]); o1[2] = f2b(acc1[2]); o1[3] = f2b(acc1[3]);
    *(us4*)vp = o0;
    *(us4*)(vp + EDIM) = o1;
}

// ---------------------------------------------------------------------------
extern "C" void kernel_launch(void* const* d_in, const int* in_sizes, int n_in,
                              void* d_out, int out_size, void* d_ws, size_t ws_size,
                              hipStream_t stream)
{
    const float* x  = (const float*)d_in[0];
    const float* Wq = (const float*)d_in[1];
    // d_in[2] = Wk (dead: attention output is multiplied by 0.0)
    const float* Wv = (const float*)d_in[3];
    const float* Wo = (const float*)d_in[4];
    const float* bo = (const float*)d_in[5];

    uint8_t* ws = (uint8_t*)d_ws;
    unsigned short* W1b = (unsigned short*)(ws);                    //  2 MB
    unsigned short* Wob = (unsigned short*)(ws + (2u  << 20));      //  2 MB
    unsigned short* T   = (unsigned short*)(ws + (4u  << 20));      //  8 MB
    unsigned short* V   = (unsigned short*)(ws + (12u << 20));      //  8 MB
    float* H    = (float*)(ws + (20u << 20));                        // 40 KB
    float* Beff = (float*)(ws + (20u << 20) + (64u << 10));          //  3 KB
    float* Corr = (float*)(ws + (20u << 20) + (96u << 10));          // 18 KB

    wprep_kernel<<<2051, 256, 0, stream>>>(
        Wq, Wv, Wo, W1b, Wob,
        (const float*)d_in[6],  (const float*)d_in[7],
        (const float*)d_in[10], (const float*)d_in[11],
        (const float*)d_in[12], (const float*)d_in[13],
        (const float*)d_in[16], (const float*)d_in[17],
        (const float*)d_in[18], (const float*)d_in[19],
        (const float*)d_in[22], (const float*)d_in[23],
        H, Beff, Corr);

    dim3 gg(EDIM / 128, MTOT / 128);   // (8, 32) = 256 blocks
    // gemm1: T = x @ W1^T, A read as raw fp32 directly from global
    gemm_nl<1, 0><<<gg, 256, 0, stream>>>(x, nullptr, nullptr,
                                          W1b, T, nullptr, nullptr);

    conv_kernel<<<1536, 256, 0, stream>>>(T, V, H, Beff, Corr);

    // gemm2: out = [T[:, :256] | V[:, 256:]] @ Wo^T + bo
    gemm_nl<0, 1><<<gg, 256, 0, stream>>>(nullptr, T, V,
                                          Wob, nullptr, (float*)d_out, bo);
}

// Round 13
// 54.187 us; speedup vs baseline: 2.0600x; 2.0600x over previous
//
#include <hip/hip_runtime.h>
#include <hip/hip_bf16.h>
#include <stdint.h>

// Problem constants: B=2, L=2048, E=1024, H=16, HD=64, G=4.
#define L_SEQ 2048
#define MTOT  4096   // B*L
#define EDIM  1024

typedef __attribute__((ext_vector_type(8))) short bf16x8;    // 8 bf16 (4 VGPRs)
typedef __attribute__((ext_vector_type(4))) float f32x4;
typedef __attribute__((ext_vector_type(16))) float f32x16;   // 32x32 MFMA acc
typedef __attribute__((ext_vector_type(4))) float float4v;
typedef __attribute__((ext_vector_type(4))) unsigned short us4;

__device__ __forceinline__ unsigned short f2b(float f) {
    union { float f; unsigned u; } v; v.f = f;
    return (unsigned short)((v.u + 0x7FFFu + ((v.u >> 16) & 1u)) >> 16);  // RNE
}
__device__ __forceinline__ float b2f(unsigned short h) {
    union { unsigned u; float f; } v; v.u = ((unsigned)h) << 16;
    return v.f;
}
__device__ __forceinline__ unsigned cvtpk(float lo, float hi) {   // RNE pack
    unsigned r;
    asm("v_cvt_pk_bf16_f32 %0, %1, %2" : "=v"(r) : "v"(lo), "v"(hi));
    return r;
}
__device__ __forceinline__ void lds16(const void* g, void* l) {
    __builtin_amdgcn_global_load_lds((const __attribute__((address_space(1))) void*)g,
                                     (__attribute__((address_space(3))) void*)l, 16, 0, 0);
}

// ---------------------------------------------------------------------------
// wprep (slim): convert W1 (stitched [Wv rows 0..255 ; Wq rows 256..1023]) to
// bf16 (blocks <1024); blocks >=1024 (3 blocks) compute the composed FIR taps.
// Wo conversion moved into conv_kernel (overlaps with FIR work).
// ---------------------------------------------------------------------------
__global__ __launch_bounds__(256) void wprep_kernel(
    const float* __restrict__ Wq, const float* __restrict__ Wv,
    unsigned short* __restrict__ W1b,
    const float* __restrict__ q3w, const float* __restrict__ q3b,
    const float* __restrict__ v3w, const float* __restrict__ v3b,
    const float* __restrict__ q5w, const float* __restrict__ q5b,
    const float* __restrict__ v5w, const float* __restrict__ v5b,
    const float* __restrict__ q7w, const float* __restrict__ q7b,
    const float* __restrict__ v7w, const float* __restrict__ v7b,
    float* __restrict__ H, float* __restrict__ Beff, float* __restrict__ Corr)
{
    if (blockIdx.x >= 1024) {
        // taps: dwconv taps h[i]=w[k-1-i]; chain h = hq (*) hv (len 2k-1<=13),
        // beff = vb + qb*sum(vw); boundary (l<k-1): intermediate zero-pad
        // drops qb for taps i>l -> Corr[l][ch] = qb*sum_{i=l+1..} hv[i].
        int ch = (blockIdx.x - 1024) * 256 + threadIdx.x;   // [0,768)
        int g = ch >> 8, d = ch & 63, k = 3 + 2 * g;
        const float* qw = (g == 0) ? q3w : (g == 1) ? q5w : q7w;
        const float* qb = (g == 0) ? q3b : (g == 1) ? q5b : q7b;
        const float* vw = (g == 0) ? v3w : (g == 1) ? v5w : v7w;
        const float* vb = (g == 0) ? v3b : (g == 1) ? v5b : v7b;

        float hq[7], hv[7];
        for (int i = 0; i < 7; ++i) { hq[i] = 0.f; hv[i] = 0.f; }
        for (int i = 0; i < k; ++i) {
            hq[i] = qw[d * k + (k - 1 - i)];
            hv[i] = vw[d * k + (k - 1 - i)];
        }
        float h[13];
        for (int i = 0; i < 13; ++i) h[i] = 0.f;
        for (int a = 0; a < 7; ++a)
            for (int b = 0; b < 7; ++b)
                h[a + b] += hq[a] * hv[b];
        for (int i = 0; i < 13; ++i) H[i * 768 + ch] = h[i];

        float sv = 0.f;
        for (int j = 0; j < k; ++j) sv += vw[d * k + j];
        Beff[ch] = qb[d] * sv + vb[d];

        for (int l = 0; l < 6; ++l) {
            float s2 = 0.f;
            for (int i = l + 1; i < 7; ++i) s2 += hv[i];
            Corr[l * 768 + ch] = qb[d] * s2;
        }
        return;
    }
    int j = (blockIdx.x * 256 + threadIdx.x) * 4;   // [0, 1M) quads
    int row = j >> 10;                              // /1024
    const float* src = (row < 256) ? Wv : Wq;       // stitched W1
    float4v v = *(const float4v*)(src + j);
    us4 o;
    o[0] = f2b(v[0]); o[1] = f2b(v[1]); o[2] = f2b(v[2]); o[3] = f2b(v[3]);
    *(us4*)(W1b + j) = o;
}

// ---------------------------------------------------------------------------
// GEMM (R10-verified structure, 32x32x16 MFMA): C[4096,1024] = A * BT^T.
//   BM=BN=128, BK=64, 512 thr = 8 waves: 2x2 spatial (wr,wc) x 2 K-halves
//   (kh). Wave tile 64x64 = 2x2 of 32x32 frags, acc f32x16[2][2].
//   Frag maps (m74/m101-verified): A/B row=lane&31, K-half=lane>>5;
//   C/D col=lane&31, row=(reg&3)+8*(reg>>2)+4*(lane>>5).
//   gload_lds staging; counted-vmcnt pipeline; XOR swizzles (both sides:
//   pre-swizzled global src + swizzled ds_read); XCD remap; K-split merge.
//   TA=1: A raw fp32 (x), frags packed via v_cvt_pk_bf16_f32. 3 bufs
//         (48KB each, 144KB LDS), depth 2, steady vmcnt(6).
//   TA=0: A bf16 per-tile src switch (t<tsplit ? Ab0 : Ab1). 4 bufs
//         (32KB each, 128KB LDS), depth 3, steady vmcnt(8), tails 4 -> 0.
// OUT_MODE 0: bf16 store. OUT_MODE 1: f32 store + bias[col].
// ---------------------------------------------------------------------------
template <int TA, int OUT_MODE>
__global__ __launch_bounds__(512, 2) void gemm_f(
    const float* __restrict__ Af,
    const unsigned short* __restrict__ Ab0, const unsigned short* __restrict__ Ab1,
    int tsplit,
    const unsigned short* __restrict__ BT,
    unsigned short* __restrict__ Cb, float* __restrict__ Cf,
    const float* __restrict__ bias)
{
    constexpr int ABUF = TA ? 49152 : 32768;   // bytes per buffer (A+B)
    constexpr int ABYT = TA ? 32768 : 16384;   // A bytes within buffer
    constexpr int NBUF = TA ? 3 : 4;           // 144KB / 128KB LDS
    __shared__ uint8_t sh[NBUF * ABUF];

    // XCD-aware remap (256 blocks, %8==0 -> bijective chunked).
    int orig = blockIdx.y * 8 + blockIdx.x;
    int wg   = (orig & 7) * 32 + (orig >> 3);
    const int m0 = (wg >> 3) * 128, n0 = (wg & 7) * 128;

    const int tid  = threadIdx.x;
    const int wid  = tid >> 6;
    const int lane = tid & 63;
    const int wr   = wid >> 2;
    const int wc   = (wid >> 1) & 1;
    const int kh   = wid & 1;
    const int l31  = lane & 31, hi = lane >> 5;

    f32x16 acc[2][2] = {};

    auto stage = [&](int buf, int t) {
        uint8_t* Abase = sh + buf * ABUF;
        uint8_t* Bbase = Abase + ABYT;
        if (TA) {
            const float* Asrc = Af + (size_t)m0 * EDIM + t * 64;
#pragma unroll
            for (int j = 0; j < 4; ++j) {
                int slot = j * 512 + tid;
                int row = slot >> 4, c = (slot & 15) ^ (row & 15);
                lds16(Asrc + (size_t)row * EDIM + c * 4,
                      Abase + j * 8192 + wid * 1024);
            }
        } else {
            const unsigned short* Asrc =
                (t < tsplit ? Ab0 : Ab1) + (size_t)m0 * EDIM + t * 64;
#pragma unroll
            for (int j = 0; j < 2; ++j) {
                int slot = j * 512 + tid;
                int row = slot >> 3, c = (slot & 7) ^ (row & 7);
                lds16(Asrc + (size_t)row * EDIM + c * 8,
                      Abase + j * 8192 + wid * 1024);
            }
        }
        const unsigned short* Bsrc = BT + (size_t)n0 * EDIM + t * 64;
#pragma unroll
        for (int j = 0; j < 2; ++j) {
            int slot = j * 512 + tid;
            int row = slot >> 3, c = (slot & 7) ^ (row & 7);
            lds16(Bsrc + (size_t)row * EDIM + c * 8,
                  Bbase + j * 8192 + wid * 1024);
        }
    };

    auto compute = [&](int buf) {
        const uint8_t* Abase = sh + buf * ABUF;
        const unsigned short* bs = (const unsigned short*)(Abase + ABYT);
#pragma unroll
        for (int s = 0; s < 2; ++s) {                  // two K=16 slabs
            bf16x8 a[2], b[2];
#pragma unroll
            for (int mi = 0; mi < 2; ++mi) {
                int row = wr * 64 + mi * 32 + l31;
                if (TA) {
                    const float* as = (const float*)Abase;
                    int c0 = kh * 8 + s * 4 + hi * 2;
                    f32x4 lo = *(const f32x4*)(as + row * 64 + ((c0 ^ (row & 15)) * 4));
                    f32x4 h4 = *(const f32x4*)(as + row * 64 + (((c0 + 1) ^ (row & 15)) * 4));
                    union { unsigned u[4]; bf16x8 v; } fu;
                    fu.u[0] = cvtpk(lo[0], lo[1]); fu.u[1] = cvtpk(lo[2], lo[3]);
                    fu.u[2] = cvtpk(h4[0], h4[1]); fu.u[3] = cvtpk(h4[2], h4[3]);
                    a[mi] = fu.v;
                } else {
                    const unsigned short* as = (const unsigned short*)Abase;
                    int cg = kh * 4 + s * 2 + hi;
                    a[mi] = *(const bf16x8*)(as + row * 64 + ((cg ^ (row & 7)) * 8));
                }
            }
#pragma unroll
            for (int ni = 0; ni < 2; ++ni) {
                int row = wc * 64 + ni * 32 + l31;
                int cg = kh * 4 + s * 2 + hi;
                b[ni] = *(const bf16x8*)(bs + row * 64 + ((cg ^ (row & 7)) * 8));
            }
#pragma unroll
            for (int mi = 0; mi < 2; ++mi)
#pragma unroll
                for (int ni = 0; ni < 2; ++ni)
                    acc[mi][ni] = __builtin_amdgcn_mfma_f32_32x32x16_bf16(a[mi], b[ni], acc[mi][ni], 0, 0, 0);
        }
    };

    const int NT = EDIM >> 6;   // 16 K-tiles
    stage(0, 0);
    stage(1, 1);
    if (!TA) stage(2, 2);
    // tile 0 landed; later tiles' loads stay in flight
    if (TA) asm volatile("s_waitcnt vmcnt(6)" ::: "memory");
    else    asm volatile("s_waitcnt vmcnt(8)" ::: "memory");
    __builtin_amdgcn_s_barrier();
    asm volatile("" ::: "memory");

    for (int t = 0; t < NT; ++t) {
        constexpr int D = NBUF - 1;            // prefetch depth (2 or 3)
        if (t + D < NT) stage((t + D) % NBUF, t + D);
        compute(t % NBUF);
        if (t + 1 < NT) {
            if (TA) {
                if (t + 2 < NT) asm volatile("s_waitcnt vmcnt(6)" ::: "memory");
                else            asm volatile("s_waitcnt vmcnt(0)" ::: "memory");
            } else {
                if (t + 3 < NT)      asm volatile("s_waitcnt vmcnt(8)" ::: "memory");
                else if (t + 2 < NT) asm volatile("s_waitcnt vmcnt(4)" ::: "memory");
                else                 asm volatile("s_waitcnt vmcnt(0)" ::: "memory");
            }
            __builtin_amdgcn_s_barrier();
            asm volatile("" ::: "memory");
        }
    }

    // ---- K-split merge: kh=1 dumps partials to LDS, kh=0 adds & stores. ----
    // acc elem i of frag (mi,ni): col = ni*32+l31,
    // row (in 64x64 tile) = mi*32 + 8*(i>>2) + 4*hi + (i&3)  [m74/m101].
    __syncthreads();   // all MFMA reads of sh complete before overwrite
    float* Mg = (float*)sh;            // 64KB needed, fits both variants
    const int mgbase = (wr * 2 + wc) * 4096;
    if (kh) {
#pragma unroll
        for (int mi = 0; mi < 2; ++mi)
#pragma unroll
            for (int ni = 0; ni < 2; ++ni) {
                int col = ni * 32 + l31;
#pragma unroll
                for (int q = 0; q < 4; ++q) {
                    int grp = mi * 8 + 2 * q + hi;
                    int adr = mgbase + col * 64 + (((grp) ^ (col & 15)) << 2);
                    f32x4 v;
                    v[0] = acc[mi][ni][q * 4 + 0]; v[1] = acc[mi][ni][q * 4 + 1];
                    v[2] = acc[mi][ni][q * 4 + 2]; v[3] = acc[mi][ni][q * 4 + 3];
                    *(f32x4*)(Mg + adr) = v;
                }
            }
    }
    __syncthreads();
    if (!kh) {
#pragma unroll
        for (int mi = 0; mi < 2; ++mi) {
#pragma unroll
            for (int ni = 0; ni < 2; ++ni) {
                int col = ni * 32 + l31;
                int gcol = n0 + wc * 64 + col;
#pragma unroll
                for (int q = 0; q < 4; ++q) {
                    int grp = mi * 8 + 2 * q + hi;
                    int adr = mgbase + col * 64 + (((grp) ^ (col & 15)) << 2);
                    f32x4 p = *(const f32x4*)(Mg + adr);
                    int rowb = m0 + wr * 64 + mi * 32 + 8 * q + 4 * hi;
#pragma unroll
                    for (int j = 0; j < 4; ++j) {
                        float v = acc[mi][ni][q * 4 + j] + p[j];
                        if (OUT_MODE == 0) {
                            Cb[(size_t)(rowb + j) * EDIM + gcol] = f2b(v);
                        } else {
                            Cf[(size_t)(rowb + j) * EDIM + gcol] = v + bias[gcol];
                        }
                    }
                }
            }
        }
    }
}

// ---------------------------------------------------------------------------
// conv: causal FIR on cols 256..1023 (blocks <1536); blocks >=1536 convert
// Wo -> bf16 (overlapped with FIR work; Wob needed only by gemm2).
// ---------------------------------------------------------------------------
__global__ __launch_bounds__(256) void conv_kernel(
    const unsigned short* __restrict__ T, unsigned short* __restrict__ V,
    const float* __restrict__ H, const float* __restrict__ Beff,
    const float* __restrict__ Corr,
    const float* __restrict__ Wo, unsigned short* __restrict__ Wob)
{
    if (blockIdx.x >= 1536) {   // Wo -> bf16 (1024 blocks, 1M quads)
        int j = ((blockIdx.x - 1536) * 256 + threadIdx.x) * 4;
        float4v v = *(const float4v*)(Wo + j);
        us4 o;
        o[0] = f2b(v[0]); o[1] = f2b(v[1]); o[2] = f2b(v[2]); o[3] = f2b(v[3]);
        *(us4*)(Wob + j) = o;
        return;
    }
    unsigned w  = blockIdx.x * 256 + threadIdx.x;   // 2048 rowpairs x 192 quads
    unsigned rp = w / 192u;
    int c4 = (int)(w - rp * 192u);
    int m  = (int)rp * 2;                           // pair never crosses batch
    int ch = c4 * 4;                                // [0,768)
    int e0 = 256 + ch;
    const unsigned short* tp = T + (size_t)m * EDIM + e0;
    unsigned short*       vp = V + (size_t)m * EDIM + e0;
    int l  = m & (L_SEQ - 1);
    float4v b4 = *(const float4v*)(Beff + ch);
    float4v acc0 = b4, acc1 = b4;

    {
        float4v h = *(const float4v*)(H + ch);      // H[0], row m+1
        us4 t = *(const us4*)(tp + EDIM);
        acc1[0] += h[0] * b2f(t[0]); acc1[1] += h[1] * b2f(t[1]);
        acc1[2] += h[2] * b2f(t[2]); acc1[3] += h[3] * b2f(t[3]);
    }
    int ni = (l < 12) ? l : 12;
    for (int i = 0; i <= ni; ++i) {                 // row m-i, taps h[i]/h[i+1]
        us4 t = *(const us4*)(tp - (size_t)i * EDIM);
        float4v h0 = *(const float4v*)(H + i * 768 + ch);
        acc0[0] += h0[0] * b2f(t[0]); acc0[1] += h0[1] * b2f(t[1]);
        acc0[2] += h0[2] * b2f(t[2]); acc0[3] += h0[3] * b2f(t[3]);
        if (i < 12) {
            float4v h1 = *(const float4v*)(H + (i + 1) * 768 + ch);
            acc1[0] += h1[0] * b2f(t[0]); acc1[1] += h1[1] * b2f(t[1]);
            acc1[2] += h1[2] * b2f(t[2]); acc1[3] += h1[3] * b2f(t[3]);
        }
    }
    if (l < 6) {   // bias boundary correction (intermediate zero-padding)
        float4v c = *(const float4v*)(Corr + l * 768 + ch);
        acc0[0] -= c[0]; acc0[1] -= c[1]; acc0[2] -= c[2]; acc0[3] -= c[3];
    }
    if (l + 1 < 6) {
        float4v c = *(const float4v*)(Corr + (l + 1) * 768 + ch);
        acc1[0] -= c[0]; acc1[1] -= c[1]; acc1[2] -= c[2]; acc1[3] -= c[3];
    }
    us4 o0, o1;
    o0[0] = f2b(acc0[0]); o0[1] = f2b(acc0[1]); o0[2] = f2b(acc0[2]); o0[3] = f2b(acc0[3]);
    o1[0] = f2b(acc1[0]); o1[1] = f2b(acc1[1]); o1[2] = f2b(acc1[2]); o1[3] = f2b(acc1[3]);
    *(us4*)vp = o0;
    *(us4*)(vp + EDIM) = o1;
}

// ---------------------------------------------------------------------------
extern "C" void kernel_launch(void* const* d_in, const int* in_sizes, int n_in,
                              void* d_out, int out_size, void* d_ws, size_t ws_size,
                              hipStream_t stream)
{
    const float* x  = (const float*)d_in[0];
    const float* Wq = (const float*)d_in[1];
    // d_in[2] = Wk (dead: attention output is multiplied by 0.0)
    const float* Wv = (const float*)d_in[3];
    const float* Wo = (const float*)d_in[4];
    const float* bo = (const float*)d_in[5];

    uint8_t* ws = (uint8_t*)d_ws;
    unsigned short* W1b = (unsigned short*)(ws);                    //  2 MB
    unsigned short* Wob = (unsigned short*)(ws + (2u  << 20));      //  2 MB
    unsigned short* T   = (unsigned short*)(ws + (4u  << 20));      //  8 MB
    unsigned short* V   = (unsigned short*)(ws + (12u << 20));      //  8 MB
    float* H    = (float*)(ws + (20u << 20));                        // 40 KB
    float* Beff = (float*)(ws + (20u << 20) + (64u << 10));          //  3 KB
    float* Corr = (float*)(ws + (20u << 20) + (96u << 10));          // 18 KB

    wprep_kernel<<<1027, 256, 0, stream>>>(
        Wq, Wv, W1b,
        (const float*)d_in[6],  (const float*)d_in[7],
        (const float*)d_in[10], (const float*)d_in[11],
        (const float*)d_in[12], (const float*)d_in[13],
        (const float*)d_in[16], (const float*)d_in[17],
        (const float*)d_in[18], (const float*)d_in[19],
        (const float*)d_in[22], (const float*)d_in[23],
        H, Beff, Corr);

    dim3 gg(EDIM / 128, MTOT / 128);   // (8, 32) = 256 blocks
    // gemm1: T = x @ W1^T, A read as raw fp32 (prep fused away)
    gemm_f<1, 0><<<gg, 512, 0, stream>>>(x, nullptr, nullptr, 0,
                                         W1b, T, nullptr, nullptr);

    conv_kernel<<<2560, 256, 0, stream>>>(T, V, H, Beff, Corr, Wo, Wob);

    // gemm2: out = [T[:, :256] | V[:, 256:]] @ Wo^T + bo  (tsplit=4 tiles)
    gemm_f<0, 1><<<gg, 512, 0, stream>>>(nullptr, T, V, 4,
                                         Wob, nullptr, (float*)d_out, bo);
}

// Round 14
// 53.855 us; speedup vs baseline: 2.0727x; 1.0062x over previous
//
#include <hip/hip_runtime.h>
#include <hip/hip_bf16.h>
#include <stdint.h>

// Problem constants: B=2, L=2048, E=1024, H=16, HD=64, G=4.
#define L_SEQ 2048
#define MTOT  4096   // B*L
#define EDIM  1024

typedef __attribute__((ext_vector_type(8))) short bf16x8;    // 8 bf16 (4 VGPRs)
typedef __attribute__((ext_vector_type(4))) float f32x4;
typedef __attribute__((ext_vector_type(16))) float f32x16;   // 32x32 MFMA acc
typedef __attribute__((ext_vector_type(4))) float float4v;
typedef __attribute__((ext_vector_type(4))) unsigned short us4;

__device__ __forceinline__ unsigned short f2b(float f) {
    union { float f; unsigned u; } v; v.f = f;
    return (unsigned short)((v.u + 0x7FFFu + ((v.u >> 16) & 1u)) >> 16);  // RNE
}
__device__ __forceinline__ float b2f(unsigned short h) {
    union { unsigned u; float f; } v; v.u = ((unsigned)h) << 16;
    return v.f;
}
__device__ __forceinline__ unsigned cvtpk(float lo, float hi) {   // RNE pack
    unsigned r;
    asm("v_cvt_pk_bf16_f32 %0, %1, %2" : "=v"(r) : "v"(lo), "v"(hi));
    return r;
}
__device__ __forceinline__ void lds16(const void* g, void* l) {
    __builtin_amdgcn_global_load_lds((const __attribute__((address_space(1))) void*)g,
                                     (__attribute__((address_space(3))) void*)l, 16, 0, 0);
}

// ---------------------------------------------------------------------------
// wprep: convert W1 (stitched [Wv rows 0..255 ; Wq rows 256..1023]) and Wo
//        to bf16. Blocks >= 2048 compute the composed FIR taps.  (R7-verified)
// ---------------------------------------------------------------------------
__global__ __launch_bounds__(256) void wprep_kernel(
    const float* __restrict__ Wq, const float* __restrict__ Wv,
    const float* __restrict__ Wo,
    unsigned short* __restrict__ W1b, unsigned short* __restrict__ Wob,
    const float* __restrict__ q3w, const float* __restrict__ q3b,
    const float* __restrict__ v3w, const float* __restrict__ v3b,
    const float* __restrict__ q5w, const float* __restrict__ q5b,
    const float* __restrict__ v5w, const float* __restrict__ v5b,
    const float* __restrict__ q7w, const float* __restrict__ q7b,
    const float* __restrict__ v7w, const float* __restrict__ v7b,
    float* __restrict__ H, float* __restrict__ Beff, float* __restrict__ Corr)
{
    if (blockIdx.x >= 2048) {
        // taps: dwconv taps h[i]=w[k-1-i]; chain h = hq (*) hv (len 2k-1<=13),
        // beff = vb + qb*sum(vw); boundary (l<k-1): intermediate zero-pad
        // drops qb for taps i>l -> Corr[l][ch] = qb*sum_{i=l+1..} hv[i].
        int ch = (blockIdx.x - 2048) * 256 + threadIdx.x;   // [0,768)
        int g = ch >> 8, d = ch & 63, k = 3 + 2 * g;
        const float* qw = (g == 0) ? q3w : (g == 1) ? q5w : q7w;
        const float* qb = (g == 0) ? q3b : (g == 1) ? q5b : q7b;
        const float* vw = (g == 0) ? v3w : (g == 1) ? v5w : v7w;
        const float* vb = (g == 0) ? v3b : (g == 1) ? v5b : v7b;

        float hq[7], hv[7];
        for (int i = 0; i < 7; ++i) { hq[i] = 0.f; hv[i] = 0.f; }
        for (int i = 0; i < k; ++i) {
            hq[i] = qw[d * k + (k - 1 - i)];
            hv[i] = vw[d * k + (k - 1 - i)];
        }
        float h[13];
        for (int i = 0; i < 13; ++i) h[i] = 0.f;
        for (int a = 0; a < 7; ++a)
            for (int b = 0; b < 7; ++b)
                h[a + b] += hq[a] * hv[b];
        for (int i = 0; i < 13; ++i) H[i * 768 + ch] = h[i];

        float sv = 0.f;
        for (int j = 0; j < k; ++j) sv += vw[d * k + j];
        Beff[ch] = qb[d] * sv + vb[d];

        for (int l = 0; l < 6; ++l) {
            float s2 = 0.f;
            for (int i = l + 1; i < 7; ++i) s2 += hv[i];
            Corr[l * 768 + ch] = qb[d] * s2;
        }
        return;
    }
    const int WQ = (EDIM * EDIM) / 4;   // 262,144 quads per matrix
    int i = blockIdx.x * 256 + threadIdx.x;
    const float* src;
    unsigned short* dst;
    int j;
    if (i < WQ) {
        j = i * 4;
        int row = j >> 10;                 // /1024
        src = (row < 256) ? Wv : Wq;       // stitched W1
        dst = W1b;
    } else {
        j = (i - WQ) * 4; src = Wo; dst = Wob;
    }
    float4v v = *(const float4v*)(src + j);
    us4 o;
    o[0] = f2b(v[0]); o[1] = f2b(v[1]); o[2] = f2b(v[2]); o[3] = f2b(v[3]);
    *(us4*)(dst + j) = o;
}

// ---------------------------------------------------------------------------
// gemm1_fused: V = conv(x @ W1^T) fused. R10-verified GEMM core (BM=BN=128,
// BK=64, 8 waves = 2x2 spatial x 2 K-halves, 32x32x16 MFMA, fp32-A staging
// via gload_lds + cvt_pk, counted-vmcnt 3-buffer pipeline, XOR swizzles,
// XCD remap, K-split merge) PLUS:
//  - FIR blocks (n0>=256): wr==0 waves also compute a 32-row HALO fragment
//    (T rows m0-32..m0-1) with A prefetched depth-1 into 2 static reg banks.
//    Halo loads are issued BEFORE stage() so the wait stays vmcnt(6) for all
//    waves (queue: [S(t+1)<=6, H(t+1)4, S(t+2)6] -> wait 6 leaves S(t+2)).
//  - epilogue: merge -> bf16 tile (160 rows incl. halo) into column-major
//    LDS [col][172] (pad for banks/alignment) -> 13-tap FIR per column ->
//    store V. Halo zeroed when m0%2048==0 (== reference tap clamping).
//  - pass-through blocks (n0<256): merge + store V directly (V=T there).
// T never touches global memory; conv kernel and its launch gap disappear.
// ---------------------------------------------------------------------------
__global__ __launch_bounds__(512, 2) void gemm1_fused(
    const float* __restrict__ Af, const unsigned short* __restrict__ BT,
    unsigned short* __restrict__ V,
    const float* __restrict__ H, const float* __restrict__ Beff,
    const float* __restrict__ Corr)
{
    constexpr int ABUF = 49152, ABYT = 32768;
    __shared__ uint8_t sh[3 * ABUF];   // 144KB

    int orig = blockIdx.y * 8 + blockIdx.x;
    int wg   = (orig & 7) * 32 + (orig >> 3);
    const int m0 = (wg >> 3) * 128, n0 = (wg & 7) * 128;
    const bool fir = (n0 >= 256);
    const int  m0h = (m0 == 0) ? 0 : (m0 - 32);      // halo base (clamped; values unused when clamped)
    const int  lbase = m0 & (L_SEQ - 1);

    const int tid  = threadIdx.x;
    const int wid  = tid >> 6;
    const int lane = tid & 63;
    const int wr   = wid >> 2;
    const int wc   = (wid >> 1) & 1;
    const int kh   = wid & 1;
    const int l31  = lane & 31, hi = lane >> 5;
    const bool firw = fir && (wr == 0);

    f32x16 acc[2][2] = {};
    f32x16 hacc[2] = {};

    // halo register banks (static names, rule #20)
    f32x4 h0s0a = {}, h0s0b = {}, h0s1a = {}, h0s1b = {};
    f32x4 h1s0a = {}, h1s0b = {}, h1s1a = {}, h1s1b = {};
    const float* hrow = Af + (size_t)(m0h + l31) * EDIM + kh * 32 + hi * 8;

#define HALOLOAD(B, t) do { if (firw) {                                     \
        const float* hp = hrow + (t) * 64;                                  \
        h##B##s0a = *(const f32x4*)(hp);      h##B##s0b = *(const f32x4*)(hp + 4);  \
        h##B##s1a = *(const f32x4*)(hp + 16); h##B##s1b = *(const f32x4*)(hp + 20); } } while (0)

    auto stage = [&](int buf, int t) {
        uint8_t* Abase = sh + buf * ABUF;
        uint8_t* Bbase = Abase + ABYT;
        const float* Asrc = Af + (size_t)m0 * EDIM + t * 64;
#pragma unroll
        for (int j = 0; j < 4; ++j) {
            int slot = j * 512 + tid;
            int row = slot >> 4, c = (slot & 15) ^ (row & 15);
            lds16(Asrc + (size_t)row * EDIM + c * 4, Abase + j * 8192 + wid * 1024);
        }
        const unsigned short* Bsrc = BT + (size_t)n0 * EDIM + t * 64;
#pragma unroll
        for (int j = 0; j < 2; ++j) {
            int slot = j * 512 + tid;
            int row = slot >> 3, c = (slot & 7) ^ (row & 7);
            lds16(Bsrc + (size_t)row * EDIM + c * 8, Bbase + j * 8192 + wid * 1024);
        }
    };

    auto compute = [&](int buf, f32x4 hs0a, f32x4 hs0b, f32x4 hs1a, f32x4 hs1b) {
        const uint8_t* Abase = sh + buf * ABUF;
        const unsigned short* bs = (const unsigned short*)(Abase + ABYT);
#pragma unroll
        for (int s = 0; s < 2; ++s) {                  // two K=16 slabs
            bf16x8 a[2], b[2];
#pragma unroll
            for (int mi = 0; mi < 2; ++mi) {
                int row = wr * 64 + mi * 32 + l31;
                const float* as = (const float*)Abase;
                int c0 = kh * 8 + s * 4 + hi * 2;
                f32x4 lo = *(const f32x4*)(as + row * 64 + ((c0 ^ (row & 15)) * 4));
                f32x4 h4 = *(const f32x4*)(as + row * 64 + (((c0 + 1) ^ (row & 15)) * 4));
                union { unsigned u[4]; bf16x8 v; } fu;
                fu.u[0] = cvtpk(lo[0], lo[1]); fu.u[1] = cvtpk(lo[2], lo[3]);
                fu.u[2] = cvtpk(h4[0], h4[1]); fu.u[3] = cvtpk(h4[2], h4[3]);
                a[mi] = fu.v;
            }
#pragma unroll
            for (int ni = 0; ni < 2; ++ni) {
                int row = wc * 64 + ni * 32 + l31;
                int cg = kh * 4 + s * 2 + hi;
                b[ni] = *(const bf16x8*)(bs + row * 64 + ((cg ^ (row & 7)) * 8));
            }
#pragma unroll
            for (int mi = 0; mi < 2; ++mi)
#pragma unroll
                for (int ni = 0; ni < 2; ++ni)
                    acc[mi][ni] = __builtin_amdgcn_mfma_f32_32x32x16_bf16(a[mi], b[ni], acc[mi][ni], 0, 0, 0);
            if (firw) {                                 // halo 32x64 fragment
                f32x4 pa = s ? hs1a : hs0a, pb = s ? hs1b : hs0b;
                union { unsigned u[4]; bf16x8 v; } hu;
                hu.u[0] = cvtpk(pa[0], pa[1]); hu.u[1] = cvtpk(pa[2], pa[3]);
                hu.u[2] = cvtpk(pb[0], pb[1]); hu.u[3] = cvtpk(pb[2], pb[3]);
                hacc[0] = __builtin_amdgcn_mfma_f32_32x32x16_bf16(hu.v, b[0], hacc[0], 0, 0, 0);
                hacc[1] = __builtin_amdgcn_mfma_f32_32x32x16_bf16(hu.v, b[1], hacc[1], 0, 0, 0);
            }
        }
    };

    const int NT = EDIM >> 6;   // 16 K-tiles (even)
    HALOLOAD(0, 0);
    stage(0, 0);
    stage(1, 1);
    asm volatile("s_waitcnt vmcnt(6)" ::: "memory");   // halo(0)+tile0 landed
    __builtin_amdgcn_s_barrier();
    asm volatile("" ::: "memory");

    for (int tt = 0; tt < NT; tt += 2) {
        // t = tt (halo bank 0)
        HALOLOAD(1, tt + 1);
        if (tt + 2 < NT) stage((tt + 2) % 3, tt + 2);
        compute(tt % 3, h0s0a, h0s0b, h0s1a, h0s1b);
        if (tt + 2 < NT) asm volatile("s_waitcnt vmcnt(6)" ::: "memory");
        else             asm volatile("s_waitcnt vmcnt(0)" ::: "memory");
        __builtin_amdgcn_s_barrier();
        asm volatile("" ::: "memory");
        // t = tt+1 (halo bank 1)
        if (tt + 2 < NT) HALOLOAD(0, tt + 2);
        if (tt + 3 < NT) stage((tt + 3) % 3, tt + 3);
        compute((tt + 1) % 3, h1s0a, h1s0b, h1s1a, h1s1b);
        if (tt + 2 < NT) {
            if (tt + 3 < NT) asm volatile("s_waitcnt vmcnt(6)" ::: "memory");
            else             asm volatile("s_waitcnt vmcnt(0)" ::: "memory");
            __builtin_amdgcn_s_barrier();
            asm volatile("" ::: "memory");
        }
    }
#undef HALOLOAD

    // ---- K-split merge + fused FIR epilogue ----
    __syncthreads();   // all MFMA reads of sh complete before overwrite
    float* Mg = (float*)sh;                 // region A: 64KB quads + 16KB halo
    const int mgbase = (wr * 2 + wc) * 4096;
    if (kh) {
#pragma unroll
        for (int mi = 0; mi < 2; ++mi)
#pragma unroll
            for (int ni = 0; ni < 2; ++ni) {
                int col = ni * 32 + l31;
#pragma unroll
                for (int q = 0; q < 4; ++q) {
                    int grp = mi * 8 + 2 * q + hi;
                    int adr = mgbase + col * 64 + (((grp) ^ (col & 15)) << 2);
                    f32x4 v;
                    v[0] = acc[mi][ni][q * 4 + 0]; v[1] = acc[mi][ni][q * 4 + 1];
                    v[2] = acc[mi][ni][q * 4 + 2]; v[3] = acc[mi][ni][q * 4 + 3];
                    *(f32x4*)(Mg + adr) = v;
                }
            }
        if (firw) {
#pragma unroll
            for (int ni = 0; ni < 2; ++ni) {
                int hcol = ni * 32 + l31;
#pragma unroll
                for (int q = 0; q < 4; ++q) {
                    int hg = 2 * q + hi;
                    int adr = 16384 + wc * 2048 + hcol * 32 + ((hg ^ (hcol & 7)) << 2);
                    f32x4 v;
                    v[0] = hacc[ni][q * 4 + 0]; v[1] = hacc[ni][q * 4 + 1];
                    v[2] = hacc[ni][q * 4 + 2]; v[3] = hacc[ni][q * 4 + 3];
                    *(f32x4*)(Mg + adr) = v;
                }
            }
        }
    }
    __syncthreads();
    if (fir) {
        unsigned short* Tl = (unsigned short*)(sh + 81920);   // [col][172] bf16
        if (!kh) {
#pragma unroll
            for (int mi = 0; mi < 2; ++mi)
#pragma unroll
                for (int ni = 0; ni < 2; ++ni) {
                    int col = wc * 64 + ni * 32 + l31;
#pragma unroll
                    for (int q = 0; q < 4; ++q) {
                        int grp = mi * 8 + 2 * q + hi;
                        int adr = mgbase + (ni * 32 + l31) * 64 + (((grp) ^ ((ni * 32 + l31) & 15)) << 2);
                        f32x4 p = *(const f32x4*)(Mg + adr);
                        int Lr = 32 + wr * 64 + mi * 32 + 8 * q + 4 * hi;
                        us4 o;
#pragma unroll
                        for (int j = 0; j < 4; ++j) o[j] = f2b(acc[mi][ni][q * 4 + j] + p[j]);
                        *(us4*)(Tl + col * 172 + Lr) = o;
                    }
                }
            if (wr == 0) {   // halo rows -> local rows 0..31
#pragma unroll
                for (int ni = 0; ni < 2; ++ni) {
                    int hcol = ni * 32 + l31;
                    int col = wc * 64 + hcol;
#pragma unroll
                    for (int q = 0; q < 4; ++q) {
                        int hg = 2 * q + hi;
                        int adr = 16384 + wc * 2048 + hcol * 32 + ((hg ^ (hcol & 7)) << 2);
                        f32x4 p = *(const f32x4*)(Mg + adr);
                        int Lr = 8 * q + 4 * hi;
                        us4 o;
#pragma unroll
                        for (int j = 0; j < 4; ++j) o[j] = f2b(hacc[ni][q * 4 + j] + p[j]);
                        *(us4*)(Tl + col * 172 + Lr) = o;
                    }
                }
            }
        }
        __syncthreads();
        // FIR: thread = (col c, row-block rb of 32). Window = 44 rows in regs.
        int c = tid & 127, rb = tid >> 7;
        int ch = n0 + c - 256;
        float h[13];
#pragma unroll
        for (int i = 0; i < 13; ++i) h[i] = H[i * 768 + ch];
        float beff = Beff[ch];
        const unsigned short* wp = Tl + c * 172 + 20 + rb * 32;
        float wf[44];
#pragma unroll
        for (int j = 0; j < 11; ++j) {
            us4 t4 = *(const us4*)(wp + j * 4);
            wf[j * 4 + 0] = b2f(t4[0]); wf[j * 4 + 1] = b2f(t4[1]);
            wf[j * 4 + 2] = b2f(t4[2]); wf[j * 4 + 3] = b2f(t4[3]);
        }
        if (lbase == 0 && rb == 0) {      // batch start: pre-batch rows = 0
#pragma unroll
            for (int j = 0; j < 12; ++j) wf[j] = 0.f;
        }
        unsigned short* vp = V + (size_t)(m0 + rb * 32) * EDIM + n0 + c;
#pragma unroll
        for (int rr = 0; rr < 32; ++rr) {
            float s = beff;
#pragma unroll
            for (int i = 0; i < 13; ++i) s += h[i] * wf[12 + rr - i];
            int l = lbase + rb * 32 + rr;
            if (l < 6) s -= Corr[l * 768 + ch];   // bias boundary correction
            vp[(size_t)rr * EDIM] = f2b(s);
        }
    } else {
        // pass-through block: V = T directly
        if (!kh) {
#pragma unroll
            for (int mi = 0; mi < 2; ++mi) {
#pragma unroll
                for (int ni = 0; ni < 2; ++ni) {
                    int col = ni * 32 + l31;
                    int gcol = n0 + wc * 64 + col;
#pragma unroll
                    for (int q = 0; q < 4; ++q) {
                        int grp = mi * 8 + 2 * q + hi;
                        int adr = mgbase + col * 64 + (((grp) ^ (col & 15)) << 2);
                        f32x4 p = *(const f32x4*)(Mg + adr);
                        int rowb = m0 + wr * 64 + mi * 32 + 8 * q + 4 * hi;
#pragma unroll
                        for (int j = 0; j < 4; ++j)
                            V[(size_t)(rowb + j) * EDIM + gcol] = f2b(acc[mi][ni][q * 4 + j] + p[j]);
                    }
                }
            }
        }
    }
}

// ---------------------------------------------------------------------------
// gemm2 (R10-verified best config): out = V @ Wo^T + bo. BM=BN=128, BK=64,
// 8 waves 2x2x2, 32x32x16 MFMA, NBUF=3, depth 2, steady vmcnt(4),
// XOR swizzles, XCD remap, K-split merge, f32 store + bias.
// ---------------------------------------------------------------------------
__global__ __launch_bounds__(512, 2) void gemm2_k(
    const unsigned short* __restrict__ Ab, const unsigned short* __restrict__ BT,
    float* __restrict__ Cf, const float* __restrict__ bias)
{
    constexpr int ABUF = 32768, ABYT = 16384;
    __shared__ uint8_t sh[3 * ABUF];   // 96KB

    int orig = blockIdx.y * 8 + blockIdx.x;
    int wg   = (orig & 7) * 32 + (orig >> 3);
    const int m0 = (wg >> 3) * 128, n0 = (wg & 7) * 128;

    const int tid  = threadIdx.x;
    const int wid  = tid >> 6;
    const int lane = tid & 63;
    const int wr   = wid >> 2;
    const int wc   = (wid >> 1) & 1;
    const int kh   = wid & 1;
    const int l31  = lane & 31, hi = lane >> 5;

    f32x16 acc[2][2] = {};

    auto stage = [&](int buf, int t) {
        uint8_t* Abase = sh + buf * ABUF;
        uint8_t* Bbase = Abase + ABYT;
        const unsigned short* Asrc = Ab + (size_t)m0 * EDIM + t * 64;
#pragma unroll
        for (int j = 0; j < 2; ++j) {
            int slot = j * 512 + tid;
            int row = slot >> 3, c = (slot & 7) ^ (row & 7);
            lds16(Asrc + (size_t)row * EDIM + c * 8, Abase + j * 8192 + wid * 1024);
        }
        const unsigned short* Bsrc = BT + (size_t)n0 * EDIM + t * 64;
#pragma unroll
        for (int j = 0; j < 2; ++j) {
            int slot = j * 512 + tid;
            int row = slot >> 3, c = (slot & 7) ^ (row & 7);
            lds16(Bsrc + (size_t)row * EDIM + c * 8, Bbase + j * 8192 + wid * 1024);
        }
    };

    auto compute = [&](int buf) {
        const uint8_t* Abase = sh + buf * ABUF;
        const unsigned short* as = (const unsigned short*)Abase;
        const unsigned short* bs = (const unsigned short*)(Abase + ABYT);
#pragma unroll
        for (int s = 0; s < 2; ++s) {
            bf16x8 a[2], b[2];
#pragma unroll
            for (int mi = 0; mi < 2; ++mi) {
                int row = wr * 64 + mi * 32 + l31;
                int cg = kh * 4 + s * 2 + hi;
                a[mi] = *(const bf16x8*)(as + row * 64 + ((cg ^ (row & 7)) * 8));
            }
#pragma unroll
            for (int ni = 0; ni < 2; ++ni) {
                int row = wc * 64 + ni * 32 + l31;
                int cg = kh * 4 + s * 2 + hi;
                b[ni] = *(const bf16x8*)(bs + row * 64 + ((cg ^ (row & 7)) * 8));
            }
#pragma unroll
            for (int mi = 0; mi < 2; ++mi)
#pragma unroll
                for (int ni = 0; ni < 2; ++ni)
                    acc[mi][ni] = __builtin_amdgcn_mfma_f32_32x32x16_bf16(a[mi], b[ni], acc[mi][ni], 0, 0, 0);
        }
    };

    const int NT = EDIM >> 6;
    stage(0, 0);
    stage(1, 1);
    asm volatile("s_waitcnt vmcnt(4)" ::: "memory");
    __builtin_amdgcn_s_barrier();
    asm volatile("" ::: "memory");

    for (int t = 0; t < NT; ++t) {
        if (t + 2 < NT) stage((t + 2) % 3, t + 2);
        compute(t % 3);
        if (t + 1 < NT) {
            if (t + 2 < NT) asm volatile("s_waitcnt vmcnt(4)" ::: "memory");
            else            asm volatile("s_waitcnt vmcnt(0)" ::: "memory");
            __builtin_amdgcn_s_barrier();
            asm volatile("" ::: "memory");
        }
    }

    __syncthreads();
    float* Mg = (float*)sh;            // 64KB
    const int mgbase = (wr * 2 + wc) * 4096;
    if (kh) {
#pragma unroll
        for (int mi = 0; mi < 2; ++mi)
#pragma unroll
            for (int ni = 0; ni < 2; ++ni) {
                int col = ni * 32 + l31;
#pragma unroll
                for (int q = 0; q < 4; ++q) {
                    int grp = mi * 8 + 2 * q + hi;
                    int adr = mgbase + col * 64 + (((grp) ^ (col & 15)) << 2);
                    f32x4 v;
                    v[0] = acc[mi][ni][q * 4 + 0]; v[1] = acc[mi][ni][q * 4 + 1];
                    v[2] = acc[mi][ni][q * 4 + 2]; v[3] = acc[mi][ni][q * 4 + 3];
                    *(f32x4*)(Mg + adr) = v;
                }
            }
    }
    __syncthreads();
    if (!kh) {
#pragma unroll
        for (int mi = 0; mi < 2; ++mi) {
#pragma unroll
            for (int ni = 0; ni < 2; ++ni) {
                int col = ni * 32 + l31;
                int gcol = n0 + wc * 64 + col;
#pragma unroll
                for (int q = 0; q < 4; ++q) {
                    int grp = mi * 8 + 2 * q + hi;
                    int adr = mgbase + col * 64 + (((grp) ^ (col & 15)) << 2);
                    f32x4 p = *(const f32x4*)(Mg + adr);
                    int rowb = m0 + wr * 64 + mi * 32 + 8 * q + 4 * hi;
#pragma unroll
                    for (int j = 0; j < 4; ++j)
                        Cf[(size_t)(rowb + j) * EDIM + gcol] = acc[mi][ni][q * 4 + j] + p[j] + bias[gcol];
                }
            }
        }
    }
}

// ---------------------------------------------------------------------------
extern "C" void kernel_launch(void* const* d_in, const int* in_sizes, int n_in,
                              void* d_out, int out_size, void* d_ws, size_t ws_size,
                              hipStream_t stream)
{
    const float* x  = (const float*)d_in[0];
    const float* Wq = (const float*)d_in[1];
    // d_in[2] = Wk (dead: attention output is multiplied by 0.0)
    const float* Wv = (const float*)d_in[3];
    const float* Wo = (const float*)d_in[4];
    const float* bo = (const float*)d_in[5];

    uint8_t* ws = (uint8_t*)d_ws;
    unsigned short* W1b = (unsigned short*)(ws);                    //  2 MB
    unsigned short* Wob = (unsigned short*)(ws + (2u  << 20));      //  2 MB
    unsigned short* V   = (unsigned short*)(ws + (4u  << 20));      //  8 MB
    float* H    = (float*)(ws + (12u << 20));                        // 40 KB
    float* Beff = (float*)(ws + (12u << 20) + (64u << 10));          //  3 KB
    float* Corr = (float*)(ws + (12u << 20) + (96u << 10));          // 18 KB

    wprep_kernel<<<2051, 256, 0, stream>>>(
        Wq, Wv, Wo, W1b, Wob,
        (const float*)d_in[6],  (const float*)d_in[7],
        (const float*)d_in[10], (const float*)d_in[11],
        (const float*)d_in[12], (const float*)d_in[13],
        (const float*)d_in[16], (const float*)d_in[17],
        (const float*)d_in[18], (const float*)d_in[19],
        (const float*)d_in[22], (const float*)d_in[23],
        H, Beff, Corr);

    dim3 gg(EDIM / 128, MTOT / 128);   // (8, 32) = 256 blocks
    // gemm1+conv fused: V = conv(x @ W1^T); T never hits global memory
    gemm1_fused<<<gg, 512, 0, stream>>>(x, W1b, V, H, Beff, Corr);

    // gemm2: out = V @ Wo^T + bo
    gemm2_k<<<gg, 512, 0, stream>>>(V, Wob, (float*)d_out, bo);
}